// Round 12
// baseline (145.630 us; speedup 1.0000x reference)
//
#include <hip/hip_runtime.h>
#include <hip/hip_bf16.h>
#include <cstddef>
#include <cstdint>

// LSTMCell fused: z = [u|h] @ [W|U]^T + bW + bE ; gates ; c/h update.
// fp32 in / fp32 out; bf16 MFMA internal, fp32 accum.
// R12: clean W-direct test (R7 minus its vmcnt-FIFO bug).
//   R5 geometry + rhythm: BM=256 x (4g x 64hc), BK=64, 512thr/8 waves,
//   A-only LDS dbuf 2x32KB. W frags direct global->VGPR from L2-resident
//   frag-interleaved Wbf3[hcol][k/8][g][8] (one base ptr, imm offsets),
//   DOUBLE-BUFFERED register sets (wEven/wOdd, 2x-unrolled loop, rule #20),
//   issued once per tile BEFORE COMPUTE, consumed after next __syncthreads
//   (its vmcnt(0) drains them — no mid-tile waits, no FIFO trap).
//   LDS pipe: 2816 -> ~1792 cyc/CU/tile (B reads+writes removed).
//   Falsifier: main >= 88us kills the LDS-pipe-bound theory.
// Pre-pass: X=[u|h]->bf16 (32MB), Wbf3 frag-interleaved (4MB), combined bias.

#define BDIM 16384
#define HDIM 512

typedef __attribute__((ext_vector_type(8))) short bf16x8;
typedef __attribute__((ext_vector_type(4))) float f32x4;

struct Params {
  const float* u;
  const float* h;
  const float* c;
  const float* W[4];
  const float* U[4];
  const float* bW[4];
  const float* bE[4];
  float* outh;
  float* outc;
};

__device__ __forceinline__ float sigmoidf_(float x) {
  return 1.0f / (1.0f + __expf(-x));
}
__device__ __forceinline__ float tanhf_(float x) {
  return 2.0f / (1.0f + __expf(-2.0f * x)) - 1.0f;
}

__device__ __forceinline__ void async16(const void* g, void* l) {
  __builtin_amdgcn_global_load_lds((const __attribute__((address_space(1))) void*)g,
                                   (__attribute__((address_space(3))) void*)l,
                                   16, 0, 0);
}

__device__ __forceinline__ bf16x8 cvt8(f32x4 a, f32x4 b) {
  bf16x8 r;
#pragma unroll
  for (int j = 0; j < 4; ++j) {
    __hip_bfloat16 t = __float2bfloat16(a[j]);
    r[j] = *reinterpret_cast<short*>(&t);
  }
#pragma unroll
  for (int j = 0; j < 4; ++j) {
    __hip_bfloat16 t = __float2bfloat16(b[j]);
    r[4 + j] = *reinterpret_cast<short*>(&t);
  }
  return r;
}

// ---------- pre-pass 1: X = [u|h] -> bf16 [16384][1024] ----------
__global__ void cvt_x_kernel(const float* __restrict__ u, const float* __restrict__ h,
                             __hip_bfloat16* __restrict__ Xbf) {
  const size_t e = ((size_t)blockIdx.x * 512 + threadIdx.x) * 8;
  const int r = (int)(e >> 10);
  const int cidx = (int)(e & 1023);
  const float* s = (cidx < 512) ? (u + (size_t)r * 512 + cidx)
                                : (h + (size_t)r * 512 + (cidx - 512));
  f32x4 v0 = *(const f32x4*)s;
  f32x4 v1 = *(const f32x4*)(s + 4);
  *(bf16x8*)(Xbf + e) = cvt8(v0, v1);
}

// ---------- pre-pass 2: Wbf3[hcol][k/8][gate][8] bf16 + combined bias ----
// element (hcol, k, g) at ((hcol*128 + k/8)*4 + g)*8 + k%8
__global__ void cvt_w_kernel(Params p, __hip_bfloat16* __restrict__ Wbf3,
                             float* __restrict__ biasC) {
  const size_t gt = (size_t)blockIdx.x * 512 + threadIdx.x;
  const int g = (int)(gt & 3);
  const int j = (int)((gt >> 2) & 127);
  const int hcol = (int)(gt >> 9);
  const int k0 = j * 8;
  const float* s = (k0 < 512) ? (p.W[g] + (size_t)hcol * 512 + k0)
                              : (p.U[g] + (size_t)hcol * 512 + (k0 - 512));
  f32x4 v0 = *(const f32x4*)s;
  f32x4 v1 = *(const f32x4*)(s + 4);
  *(bf16x8*)(Wbf3 + gt * 8) = cvt8(v0, v1);
  if (gt < 2048) {
    const int bg = (int)(gt >> 9), hh = (int)(gt & 511);
    biasC[gt] = p.bW[bg][hh] + p.bE[bg][hh];
  }
}

// ---------- main GEMM + fused gates ----------
__launch_bounds__(512, 2)
__global__ void lstm_main_kernel(const __hip_bfloat16* __restrict__ Xbf,
                                 const __hip_bfloat16* __restrict__ Wbf3,
                                 const float* __restrict__ biasC,
                                 const float* __restrict__ c,
                                 float* __restrict__ outh,
                                 float* __restrict__ outc) {
  // LDS: A only, 2 bufs x [256][64] bf16 = 64 KB
  __shared__ char smem[65536];

  const int tid = threadIdx.x;
  const int w   = tid >> 6;   // 0..7
  const int l   = tid & 63;
  const int wm  = w >> 2;     // 0..1 : 128-row half
  const int wh  = w & 3;      // 0..3 : 16-hcol group

  // XCD swizzle: 512 blocks, 8 XCDs -> XCD x owns h_tile x (512KB L2 slice)
  const int swz = (blockIdx.x & 7) * 64 + (blockIdx.x >> 3);
  const int m_tile = swz & 63;
  const int h_tile = swz >> 6;
  const int rowA0 = m_tile * 256;
  const int nrow0 = h_tile * 64;

  const int rsub = l >> 3;             // 0..7 row-within-8
  const int slot = (l & 7) ^ rsub;     // pre-swizzled source 16B slot

  // A staging source (advance 64 bf16 = 128 B per K-tile); wave w: rows w*32..
  const __hip_bfloat16* gpA =
      Xbf + (size_t)(rowA0 + w * 32 + rsub) * 1024 + slot * 8;
  const int dbase = (w * 32 + rsub) * 128 + (l & 7) * 16;

  // W frag base: hcol = nrow0 + wh*16 + (l&15), j-slot base = l>>4.
  // frag(t,kk,g) at wpB + t*256 + kk*128 + g*8 elems
  const __hip_bfloat16* wpB =
      Wbf3 + ((size_t)(nrow0 + wh * 16 + (l & 15)) * 128 + (l >> 4)) * 32;

  f32x4 acc[4][8] = {};        // [gate][m-frag] = 128 regs
  bf16x8 wEven[8], wOdd[8];    // W frag sets [g][kk], 32+32 regs

  auto STAGE = [&](int t, char* buf) {
#pragma unroll
    for (int j = 0; j < 4; ++j)
      async16(gpA + (size_t)(j * 8) * 1024 + t * 64, buf + dbase + j * 8 * 128);
  };
  auto LOADW = [&](int t, bf16x8* wd) {
    const __hip_bfloat16* b = wpB + t * 256;
#pragma unroll
    for (int g = 0; g < 4; ++g) {
      wd[g * 2]     = *(const bf16x8*)(b + g * 8);
      wd[g * 2 + 1] = *(const bf16x8*)(b + 128 + g * 8);
    }
  };

  const int xr  = (l & 7) << 4;   // read-side LDS swizzle
  const int ar  = l & 15;
  const int kof = (l >> 4) * 16;

  auto COMPUTE = [&](const char* buf, const bf16x8* wd) {
#pragma unroll
    for (int kk = 0; kk < 2; ++kk) {
      const int kb = (kk * 64 + kof) ^ xr;
      bf16x8 av[8];
#pragma unroll
      for (int mf = 0; mf < 8; ++mf)
        av[mf] = *(const bf16x8*)(buf + (wm * 128 + mf * 16 + ar) * 128 + kb);
#pragma unroll
      for (int g = 0; g < 4; ++g)
#pragma unroll
        for (int mf = 0; mf < 8; ++mf)
          acc[g][mf] = __builtin_amdgcn_mfma_f32_16x16x32_bf16(
              av[mf], wd[g * 2 + kk], acc[g][mf], 0, 0, 0);
    }
  };

  char* buf0 = smem;
  char* buf1 = smem + 32768;

  STAGE(0, buf0);
  LOADW(0, wEven);
  __syncthreads();  // vmcnt(0) drain + barrier

  for (int tt = 0; tt < 8; ++tt) {
    const int t = tt * 2;
    // even tile t: compute buf0/wEven; prefetch t+1 (A->buf1, W->wOdd)
    STAGE(t + 1, buf1);
    LOADW(t + 1, wOdd);
    COMPUTE(buf0, wEven);
    __syncthreads();
    // odd tile t+1: compute buf1/wOdd; prefetch t+2 (A->buf0, W->wEven)
    if (t + 2 < 16) {
      STAGE(t + 2, buf0);
      LOADW(t + 2, wEven);
    }
    COMPUTE(buf1, wOdd);
    __syncthreads();
  }

  // ---- fused epilogue ----
  // C/D layout: col = lane&15, row = (lane>>4)*4 + reg   [m89/m91]
  const int lr = (l >> 4) * 4;
  const int lc = l & 15;
  const int hc = nrow0 + wh * 16 + lc;
  const float bzi = biasC[0 * 512 + hc];
  const float bzf = biasC[1 * 512 + hc];
  const float bzg = biasC[2 * 512 + hc];
  const float bzo = biasC[3 * 512 + hc];
#pragma unroll
  for (int mf = 0; mf < 8; ++mf) {
#pragma unroll
    for (int j = 0; j < 4; ++j) {
      const int row = rowA0 + wm * 128 + mf * 16 + lr + j;
      const float zi = acc[0][mf][j] + bzi;
      const float zf = acc[1][mf][j] + bzf;
      const float zg = acc[2][mf][j] + bzg;
      const float zo = acc[3][mf][j] + bzo;
      const float ig = sigmoidf_(zi);
      const float fg = sigmoidf_(zf);
      const float gg = tanhf_(zg);
      const float og = sigmoidf_(zo);
      const size_t idx = (size_t)row * 512 + hc;
      const float cv = c[idx];
      const float cn = fg * cv + ig * gg;
      const float hn = og * tanhf_(cn);
      outh[idx] = hn;
      outc[idx] = cn;
    }
  }
}

// ---------- fallback: proven R2 kernel ----------
__launch_bounds__(256, 2)
__global__ void lstm_legacy_kernel(Params p) {
  __shared__ char smem[32768];
  __shared__ float biasLDS[4][32];

  const int tid = threadIdx.x;
  const int w   = tid >> 6;
  const int l   = tid & 63;
  const int m_tile = blockIdx.x & 127;
  const int h_tile = blockIdx.x >> 7;

  char* smemA = smem;
  char* smemW = smem + 16384;
  const int rowA0 = m_tile * 128;
  const int nrow0 = h_tile * 32;

  if (tid < 128) {
    const int g = tid >> 5, hh = tid & 31;
    const int hcb = nrow0 + hh;
    biasLDS[g][hh] = p.bW[g][hcb] + p.bE[g][hcb];
  }

  const int sr = tid >> 3;
  const int sc = tid & 7;
  const int wcol = (sc * 16) ^ ((sr & 7) << 4);

  f32x4 acc[4][2][2] = {};
  f32x4 rg[16];

  auto load_tile = [&](int kt) {
    const float* sA = (kt < 8) ? p.u : p.h;
    const int kc = (kt & 7) * 64;
#pragma unroll
    for (int cc = 0; cc < 4; ++cc) {
      const float* gp = sA + (size_t)(rowA0 + cc * 32 + sr) * 512 + kc + sc * 8;
      rg[cc * 2]     = *(const f32x4*)gp;
      rg[cc * 2 + 1] = *(const f32x4*)(gp + 4);
    }
#pragma unroll
    for (int cc = 0; cc < 4; ++cc) {
      const float* sW = (kt < 8) ? p.W[cc] : p.U[cc];
      const float* gp = sW + (size_t)(nrow0 + sr) * 512 + kc + sc * 8;
      rg[8 + cc * 2]     = *(const f32x4*)gp;
      rg[8 + cc * 2 + 1] = *(const f32x4*)(gp + 4);
    }
  };

  auto write_tile = [&]() {
#pragma unroll
    for (int cc = 0; cc < 4; ++cc)
      *(bf16x8*)(smemA + (cc * 32 + sr) * 128 + wcol) = cvt8(rg[cc * 2], rg[cc * 2 + 1]);
#pragma unroll
    for (int cc = 0; cc < 4; ++cc)
      *(bf16x8*)(smemW + (cc * 32 + sr) * 128 + wcol) = cvt8(rg[8 + cc * 2], rg[8 + cc * 2 + 1]);
  };

  const int xr = (l & 7) << 4;

  auto compute = [&]() {
#pragma unroll
    for (int kk = 0; kk < 2; ++kk) {
      const int kb = (kk * 64 + (l >> 4) * 16) ^ xr;
      bf16x8 a0 = *(const bf16x8*)(smemA + (w * 32 +      (l & 15)) * 128 + kb);
      bf16x8 a1 = *(const bf16x8*)(smemA + (w * 32 + 16 + (l & 15)) * 128 + kb);
#pragma unroll
      for (int g = 0; g < 4; ++g) {
#pragma unroll
        for (int ni = 0; ni < 2; ++ni) {
          bf16x8 b = *(const bf16x8*)(smemW + (g * 32 + ni * 16 + (l & 15)) * 128 + kb);
          acc[g][0][ni] = __builtin_amdgcn_mfma_f32_16x16x32_bf16(a0, b, acc[g][0][ni], 0, 0, 0);
          acc[g][1][ni] = __builtin_amdgcn_mfma_f32_16x16x32_bf16(a1, b, acc[g][1][ni], 0, 0, 0);
        }
      }
    }
  };

  load_tile(0);
  for (int kt = 0; kt < 16; ++kt) {
    write_tile();
    __syncthreads();
    if (kt < 15) load_tile(kt + 1);
    compute();
    __syncthreads();
  }

  const int lr = (l >> 4) * 4;
  const int lc = l & 15;
#pragma unroll
  for (int mi = 0; mi < 2; ++mi) {
#pragma unroll
    for (int j = 0; j < 4; ++j) {
      const int row = rowA0 + w * 32 + mi * 16 + lr + j;
#pragma unroll
      for (int ni = 0; ni < 2; ++ni) {
        const int hcc = nrow0 + ni * 16 + lc;
        const int bcol = ni * 16 + lc;
        const float zi = acc[0][mi][ni][j] + biasLDS[0][bcol];
        const float zf = acc[1][mi][ni][j] + biasLDS[1][bcol];
        const float zg = acc[2][mi][ni][j] + biasLDS[2][bcol];
        const float zo = acc[3][mi][ni][j] + biasLDS[3][bcol];
        const float ig = sigmoidf_(zi);
        const float fg = sigmoidf_(zf);
        const float gg = tanhf_(zg);
        const float og = sigmoidf_(zo);
        const size_t idx = (size_t)row * 512 + hcc;
        const float cv = p.c[idx];
        const float cn = fg * cv + ig * gg;
        const float hn = og * tanhf_(cn);
        p.outh[idx] = hn;
        p.outc[idx] = cn;
      }
    }
  }
}

extern "C" void kernel_launch(void* const* d_in, const int* in_sizes, int n_in,
                              void* d_out, int out_size, void* d_ws, size_t ws_size,
                              hipStream_t stream) {
  Params p;
  p.u = (const float*)d_in[0];
  p.h = (const float*)d_in[1];
  p.c = (const float*)d_in[2];
  p.W[0] = (const float*)d_in[3];
  p.bW[0] = (const float*)d_in[4];
  p.W[1] = (const float*)d_in[5];
  p.bW[1] = (const float*)d_in[6];
  p.W[2] = (const float*)d_in[7];
  p.bW[2] = (const float*)d_in[8];
  p.W[3] = (const float*)d_in[9];
  p.bW[3] = (const float*)d_in[10];
  p.U[0] = (const float*)d_in[11];
  p.U[1] = (const float*)d_in[12];
  p.U[2] = (const float*)d_in[13];
  p.U[3] = (const float*)d_in[14];
  p.bE[0] = (const float*)d_in[15];
  p.bE[1] = (const float*)d_in[16];
  p.bE[2] = (const float*)d_in[17];
  p.bE[3] = (const float*)d_in[18];
  p.outh = (float*)d_out;
  p.outc = (float*)d_out + (size_t)BDIM * HDIM;

  const size_t X_BYTES = (size_t)BDIM * 1024 * 2;        // 32 MB
  const size_t W_BYTES = (size_t)4 * 512 * 1024 * 2;     // 4 MB
  const size_t B_BYTES = 2048 * 4;                       // 8 KB
  if (ws_size >= X_BYTES + W_BYTES + B_BYTES) {
    __hip_bfloat16* Xbf = (__hip_bfloat16*)d_ws;
    __hip_bfloat16* Wbf3 = (__hip_bfloat16*)((char*)d_ws + X_BYTES);
    float* biasC = (float*)((char*)d_ws + X_BYTES + W_BYTES);

    hipLaunchKernelGGL(cvt_x_kernel, dim3(4096), dim3(512), 0, stream, p.u, p.h, Xbf);
    hipLaunchKernelGGL(cvt_w_kernel, dim3(512), dim3(512), 0, stream, p, Wbf3, biasC);
    hipLaunchKernelGGL(lstm_main_kernel, dim3(512), dim3(512), 0, stream,
                       Xbf, Wbf3, biasC, p.c, p.outh, p.outc);
  } else {
    hipLaunchKernelGGL(lstm_legacy_kernel, dim3(2048), dim3(256), 0, stream, p);
  }
}

// Round 13
// 130.717 us; speedup vs baseline: 1.1141x; 1.1141x over previous
//
#include <hip/hip_runtime.h>
#include <hip/hip_bf16.h>
#include <cstddef>
#include <cstdint>

// LSTMCell fused: z = [u|h] @ [W|U]^T + bW + bE ; gates ; c/h update.
// fp32 in / fp32 out; bf16 MFMA internal, fp32 accum.
// R13: R5 (best, 90.8us main) + address-hoisted LDS reads + fused prepass.
//   - 8 loop-invariant base pointers (buf x {A,B} x {kb0,kb1}); all ds_reads
//     become base+const -> ds_read offset: immediates. Loop unrolled x2 so
//     buffer pointers are static (rule #20). Attacks VALUBusy 36% (> Mfma 31%).
//   - Single fused prepass kernel (X-cvt + W-cvt + bias), one launch.
//   Structure/schedule otherwise IDENTICAL to R5 (8 variants tried, none beat
//   it; W-direct falsified 3x: scattered VMEM B-frag loads are the mechanism).

#define BDIM 16384
#define HDIM 512

typedef __attribute__((ext_vector_type(8))) short bf16x8;
typedef __attribute__((ext_vector_type(4))) float f32x4;

struct Params {
  const float* u;
  const float* h;
  const float* c;
  const float* W[4];
  const float* U[4];
  const float* bW[4];
  const float* bE[4];
  float* outh;
  float* outc;
};

__device__ __forceinline__ float sigmoidf_(float x) {
  return 1.0f / (1.0f + __expf(-x));
}
__device__ __forceinline__ float tanhf_(float x) {
  return 2.0f / (1.0f + __expf(-2.0f * x)) - 1.0f;
}

__device__ __forceinline__ void async16(const void* g, void* l) {
  __builtin_amdgcn_global_load_lds((const __attribute__((address_space(1))) void*)g,
                                   (__attribute__((address_space(3))) void*)l,
                                   16, 0, 0);
}

__device__ __forceinline__ bf16x8 cvt8(f32x4 a, f32x4 b) {
  bf16x8 r;
#pragma unroll
  for (int j = 0; j < 4; ++j) {
    __hip_bfloat16 t = __float2bfloat16(a[j]);
    r[j] = *reinterpret_cast<short*>(&t);
  }
#pragma unroll
  for (int j = 0; j < 4; ++j) {
    __hip_bfloat16 t = __float2bfloat16(b[j]);
    r[4 + j] = *reinterpret_cast<short*>(&t);
  }
  return r;
}

// ---------- fused pre-pass: X=[u|h]->bf16 ; Wbf[g][hcol][k'] ; bias ----------
__global__ void cvt_all_kernel(Params p, __hip_bfloat16* __restrict__ Xbf,
                               __hip_bfloat16* __restrict__ Wbf,
                               float* __restrict__ biasC) {
  const int b = blockIdx.x;
  if (b < 4096) {
    // X part: [16384][1024] bf16
    const size_t e = ((size_t)b * 512 + threadIdx.x) * 8;
    const int r = (int)(e >> 10);
    const int cidx = (int)(e & 1023);
    const float* s = (cidx < 512) ? (p.u + (size_t)r * 512 + cidx)
                                  : (p.h + (size_t)r * 512 + (cidx - 512));
    f32x4 v0 = *(const f32x4*)s;
    f32x4 v1 = *(const f32x4*)(s + 4);
    *(bf16x8*)(Xbf + e) = cvt8(v0, v1);
  } else {
    // W part: Wbf[g][hcol][k'] + combined bias
    const size_t gt = (size_t)(b - 4096) * 512 + threadIdx.x;
    const size_t e = gt * 8;
    const int g = (int)(e >> 19);
    const int rem = (int)(e & 524287);
    const int hcol = rem >> 10;
    const int k = rem & 1023;
    const float* s = (k < 512) ? (p.W[g] + (size_t)hcol * 512 + k)
                               : (p.U[g] + (size_t)hcol * 512 + (k - 512));
    f32x4 v0 = *(const f32x4*)s;
    f32x4 v1 = *(const f32x4*)(s + 4);
    *(bf16x8*)(Wbf + e) = cvt8(v0, v1);
    if (gt < 2048) {
      const int bg = (int)(gt >> 9), hh = (int)(gt & 511);
      biasC[gt] = p.bW[bg][hh] + p.bE[bg][hh];
    }
  }
}

// ---------- main GEMM + fused gates ----------
__launch_bounds__(512, 2)
__global__ void lstm_main_kernel(const __hip_bfloat16* __restrict__ Xbf,
                                 const __hip_bfloat16* __restrict__ Wbf,
                                 const float* __restrict__ biasC,
                                 const float* __restrict__ c,
                                 float* __restrict__ outh,
                                 float* __restrict__ outc) {
  // 2 bufs x (A [256][64] bf16 32KB + W [256][64] bf16 32KB) = 128 KB
  __shared__ char smem[131072];

  const int tid = threadIdx.x;
  const int w   = tid >> 6;   // 0..7
  const int l   = tid & 63;
  const int wm  = w >> 2;     // 0..1 : 128-row half
  const int wh  = w & 3;      // 0..3 : 16-hcol group

  // XCD swizzle: 512 blocks, 8 XCDs -> XCD x owns h_tile x (512KB L2 slice)
  const int swz = (blockIdx.x & 7) * 64 + (blockIdx.x >> 3);
  const int m_tile = swz & 63;
  const int h_tile = swz >> 6;
  const int rowA0 = m_tile * 256;
  const int nrow0 = h_tile * 64;

  const int rsub = l >> 3;             // 0..7 row-within-8
  const int slot = (l & 7) ^ rsub;     // pre-swizzled source 16B slot
  const int gW = w >> 1;               // gate staged by this wave
  const int hrel0 = (w & 1) * 32;

  // staging source base pointers (advance t*128 B per K-tile)
  const __hip_bfloat16* gpA[4];
  const __hip_bfloat16* gpW[4];
#pragma unroll
  for (int j = 0; j < 4; ++j) {
    gpA[j] = Xbf + (size_t)(rowA0 + w * 32 + j * 8 + rsub) * 1024 + slot * 8;
    gpW[j] = Wbf + (size_t)(gW * 512 + nrow0 + hrel0 + j * 8 + rsub) * 1024 + slot * 8;
  }

  f32x4 acc[4][8] = {};  // [gate][m-frag]

  // ---- loop-invariant LDS read base pointers (8 total) ----
  const int xr  = (l & 7) << 4;
  const int ar  = l & 15;
  const int kb0 = ((l >> 4) * 16) ^ xr;
  const int kb1 = (64 + (l >> 4) * 16) ^ xr;
  const char* aK0_0 = smem + (wm * 128 + ar) * 128 + kb0;            // buf0 A kk0
  const char* aK1_0 = smem + (wm * 128 + ar) * 128 + kb1;            // buf0 A kk1
  const char* bK0_0 = smem + 32768 + (wh * 16 + ar) * 128 + kb0;     // buf0 B kk0
  const char* bK1_0 = smem + 32768 + (wh * 16 + ar) * 128 + kb1;     // buf0 B kk1
  const char* aK0_1 = aK0_0 + 65536;                                 // buf1 ...
  const char* aK1_1 = aK1_0 + 65536;
  const char* bK0_1 = bK0_0 + 65536;
  const char* bK1_1 = bK1_0 + 65536;

  auto STAGE = [&](int t, char* bufA) {
    char* bufW = bufA + 32768;
#pragma unroll
    for (int j = 0; j < 4; ++j) {
      async16(gpA[j] + t * 64, bufA + (w * 32 + j * 8) * 128);
      async16(gpW[j] + t * 64, bufW + (w * 32 + j * 8) * 128);
    }
  };

  auto COMPUTE = [&](const char* aK0, const char* aK1,
                     const char* bK0, const char* bK1) {
    bf16x8 av[8], bv[4];
    // kk = 0 : all offsets compile-time immediates
#pragma unroll
    for (int mf = 0; mf < 8; ++mf) av[mf] = *(const bf16x8*)(aK0 + mf * 2048);
#pragma unroll
    for (int g = 0; g < 4; ++g) bv[g] = *(const bf16x8*)(bK0 + g * 8192);
#pragma unroll
    for (int g = 0; g < 4; ++g)
#pragma unroll
      for (int mf = 0; mf < 8; ++mf)
        acc[g][mf] = __builtin_amdgcn_mfma_f32_16x16x32_bf16(av[mf], bv[g], acc[g][mf], 0, 0, 0);
    // kk = 1
#pragma unroll
    for (int mf = 0; mf < 8; ++mf) av[mf] = *(const bf16x8*)(aK1 + mf * 2048);
#pragma unroll
    for (int g = 0; g < 4; ++g) bv[g] = *(const bf16x8*)(bK1 + g * 8192);
#pragma unroll
    for (int g = 0; g < 4; ++g)
#pragma unroll
      for (int mf = 0; mf < 8; ++mf)
        acc[g][mf] = __builtin_amdgcn_mfma_f32_16x16x32_bf16(av[mf], bv[g], acc[g][mf], 0, 0, 0);
  };

  char* buf0 = smem;
  char* buf1 = smem + 65536;

  STAGE(0, buf0);
  __syncthreads();

  for (int tt = 0; tt < 8; ++tt) {
    const int t = tt * 2;
    // even tile t: compute buf0; prefetch t+1 -> buf1
    STAGE(t + 1, buf1);
    COMPUTE(aK0_0, aK1_0, bK0_0, bK1_0);
    __syncthreads();
    // odd tile t+1: compute buf1; prefetch t+2 -> buf0
    if (tt < 7) STAGE(t + 2, buf0);
    COMPUTE(aK0_1, aK1_1, bK0_1, bK1_1);
    __syncthreads();
  }

  // ---- fused epilogue ----
  // C/D layout: col = lane&15, row = (lane>>4)*4 + reg   [m89/m91]
  const int lr = (l >> 4) * 4;
  const int lc = l & 15;
  const int hc = nrow0 + wh * 16 + lc;
  const float bzi = biasC[0 * 512 + hc];
  const float bzf = biasC[1 * 512 + hc];
  const float bzg = biasC[2 * 512 + hc];
  const float bzo = biasC[3 * 512 + hc];
#pragma unroll
  for (int mf = 0; mf < 8; ++mf) {
#pragma unroll
    for (int j = 0; j < 4; ++j) {
      const int row = rowA0 + wm * 128 + mf * 16 + lr + j;
      const float zi = acc[0][mf][j] + bzi;
      const float zf = acc[1][mf][j] + bzf;
      const float zg = acc[2][mf][j] + bzg;
      const float zo = acc[3][mf][j] + bzo;
      const float ig = sigmoidf_(zi);
      const float fg = sigmoidf_(zf);
      const float gg = tanhf_(zg);
      const float og = sigmoidf_(zo);
      const size_t idx = (size_t)row * 512 + hc;
      const float cv = c[idx];
      const float cn = fg * cv + ig * gg;
      const float hn = og * tanhf_(cn);
      outh[idx] = hn;
      outc[idx] = cn;
    }
  }
}

// ---------- fallback: proven R2 kernel ----------
__launch_bounds__(256, 2)
__global__ void lstm_legacy_kernel(Params p) {
  __shared__ char smem[32768];
  __shared__ float biasLDS[4][32];

  const int tid = threadIdx.x;
  const int w   = tid >> 6;
  const int l   = tid & 63;
  const int m_tile = blockIdx.x & 127;
  const int h_tile = blockIdx.x >> 7;

  char* smemA = smem;
  char* smemW = smem + 16384;
  const int rowA0 = m_tile * 128;
  const int nrow0 = h_tile * 32;

  if (tid < 128) {
    const int g = tid >> 5, hh = tid & 31;
    const int hcb = nrow0 + hh;
    biasLDS[g][hh] = p.bW[g][hcb] + p.bE[g][hcb];
  }

  const int sr = tid >> 3;
  const int sc = tid & 7;
  const int wcol = (sc * 16) ^ ((sr & 7) << 4);

  f32x4 acc[4][2][2] = {};
  f32x4 rg[16];

  auto load_tile = [&](int kt) {
    const float* sA = (kt < 8) ? p.u : p.h;
    const int kc = (kt & 7) * 64;
#pragma unroll
    for (int cc = 0; cc < 4; ++cc) {
      const float* gp = sA + (size_t)(rowA0 + cc * 32 + sr) * 512 + kc + sc * 8;
      rg[cc * 2]     = *(const f32x4*)gp;
      rg[cc * 2 + 1] = *(const f32x4*)(gp + 4);
    }
#pragma unroll
    for (int cc = 0; cc < 4; ++cc) {
      const float* sW = (kt < 8) ? p.W[cc] : p.U[cc];
      const float* gp = sW + (size_t)(nrow0 + sr) * 512 + kc + sc * 8;
      rg[8 + cc * 2]     = *(const f32x4*)gp;
      rg[8 + cc * 2 + 1] = *(const f32x4*)(gp + 4);
    }
  };

  auto write_tile = [&]() {
#pragma unroll
    for (int cc = 0; cc < 4; ++cc)
      *(bf16x8*)(smemA + (cc * 32 + sr) * 128 + wcol) = cvt8(rg[cc * 2], rg[cc * 2 + 1]);
#pragma unroll
    for (int cc = 0; cc < 4; ++cc)
      *(bf16x8*)(smemW + (cc * 32 + sr) * 128 + wcol) = cvt8(rg[8 + cc * 2], rg[8 + cc * 2 + 1]);
  };

  const int xr = (l & 7) << 4;

  auto compute = [&]() {
#pragma unroll
    for (int kk = 0; kk < 2; ++kk) {
      const int kb = (kk * 64 + (l >> 4) * 16) ^ xr;
      bf16x8 a0 = *(const bf16x8*)(smemA + (w * 32 +      (l & 15)) * 128 + kb);
      bf16x8 a1 = *(const bf16x8*)(smemA + (w * 32 + 16 + (l & 15)) * 128 + kb);
#pragma unroll
      for (int g = 0; g < 4; ++g) {
#pragma unroll
        for (int ni = 0; ni < 2; ++ni) {
          bf16x8 b = *(const bf16x8*)(smemW + (g * 32 + ni * 16 + (l & 15)) * 128 + kb);
          acc[g][0][ni] = __builtin_amdgcn_mfma_f32_16x16x32_bf16(a0, b, acc[g][0][ni], 0, 0, 0);
          acc[g][1][ni] = __builtin_amdgcn_mfma_f32_16x16x32_bf16(a1, b, acc[g][1][ni], 0, 0, 0);
        }
      }
    }
  };

  load_tile(0);
  for (int kt = 0; kt < 16; ++kt) {
    write_tile();
    __syncthreads();
    if (kt < 15) load_tile(kt + 1);
    compute();
    __syncthreads();
  }

  const int lr = (l >> 4) * 4;
  const int lc = l & 15;
#pragma unroll
  for (int mi = 0; mi < 2; ++mi) {
#pragma unroll
    for (int j = 0; j < 4; ++j) {
      const int row = rowA0 + w * 32 + mi * 16 + lr + j;
#pragma unroll
      for (int ni = 0; ni < 2; ++ni) {
        const int hcc = nrow0 + ni * 16 + lc;
        const int bcol = ni * 16 + lc;
        const float zi = acc[0][mi][ni][j] + biasLDS[0][bcol];
        const float zf = acc[1][mi][ni][j] + biasLDS[1][bcol];
        const float zg = acc[2][mi][ni][j] + biasLDS[2][bcol];
        const float zo = acc[3][mi][ni][j] + biasLDS[3][bcol];
        const float ig = sigmoidf_(zi);
        const float fg = sigmoidf_(zf);
        const float gg = tanhf_(zg);
        const float og = sigmoidf_(zo);
        const size_t idx = (size_t)row * 512 + hcc;
        const float cv = p.c[idx];
        const float cn = fg * cv + ig * gg;
        const float hn = og * tanhf_(cn);
        p.outh[idx] = hn;
        p.outc[idx] = cn;
      }
    }
  }
}

extern "C" void kernel_launch(void* const* d_in, const int* in_sizes, int n_in,
                              void* d_out, int out_size, void* d_ws, size_t ws_size,
                              hipStream_t stream) {
  Params p;
  p.u = (const float*)d_in[0];
  p.h = (const float*)d_in[1];
  p.c = (const float*)d_in[2];
  p.W[0] = (const float*)d_in[3];
  p.bW[0] = (const float*)d_in[4];
  p.W[1] = (const float*)d_in[5];
  p.bW[1] = (const float*)d_in[6];
  p.W[2] = (const float*)d_in[7];
  p.bW[2] = (const float*)d_in[8];
  p.W[3] = (const float*)d_in[9];
  p.bW[3] = (const float*)d_in[10];
  p.U[0] = (const float*)d_in[11];
  p.U[1] = (const float*)d_in[12];
  p.U[2] = (const float*)d_in[13];
  p.U[3] = (const float*)d_in[14];
  p.bE[0] = (const float*)d_in[15];
  p.bE[1] = (const float*)d_in[16];
  p.bE[2] = (const float*)d_in[17];
  p.bE[3] = (const float*)d_in[18];
  p.outh = (float*)d_out;
  p.outc = (float*)d_out + (size_t)BDIM * HDIM;

  const size_t X_BYTES = (size_t)BDIM * 1024 * 2;        // 32 MB
  const size_t W_BYTES = (size_t)4 * 512 * 1024 * 2;     // 4 MB
  const size_t B_BYTES = 2048 * 4;                       // 8 KB
  if (ws_size >= X_BYTES + W_BYTES + B_BYTES) {
    __hip_bfloat16* Xbf = (__hip_bfloat16*)d_ws;
    __hip_bfloat16* Wbf = (__hip_bfloat16*)((char*)d_ws + X_BYTES);
    float* biasC = (float*)((char*)d_ws + X_BYTES + W_BYTES);

    hipLaunchKernelGGL(cvt_all_kernel, dim3(4608), dim3(512), 0, stream,
                       p, Xbf, Wbf, biasC);
    hipLaunchKernelGGL(lstm_main_kernel, dim3(512), dim3(512), 0, stream,
                       Xbf, Wbf, biasC, p.c, p.outh, p.outc);
  } else {
    hipLaunchKernelGGL(lstm_legacy_kernel, dim3(2048), dim3(256), 0, stream, p);
  }
}